// Round 21
// baseline (1888.916 us; speedup 1.0000x reference)
//
#include <hip/hip_runtime.h>
#include <math.h>

using bf16x8 = __attribute__((ext_vector_type(8))) short;
using f32x4  = __attribute__((ext_vector_type(4))) float;
using u16x8  = __attribute__((ext_vector_type(8))) unsigned short;

__device__ __forceinline__ float b2f(unsigned short u){
  union{float f; unsigned int i;} x; x.i = ((unsigned int)u)<<16; return x.f;
}
__device__ __forceinline__ unsigned short f2b(float f){
  union{float f; unsigned int i;} x; x.f = f;
  unsigned int r = x.i + 0x7fffu + ((x.i>>16)&1u);
  return (unsigned short)(r>>16);
}
__device__ __forceinline__ float gelu_tanh(float x){
  float x3 = x*x*x;
  return 0.5f*x*(1.0f + tanhf(0.79788456080286535588f*(x + 0.044715f*x3)));
}
__device__ __forceinline__ float wave_sum(float v){
  #pragma unroll
  for (int o=32;o>0;o>>=1) v += __shfl_down(v,o);
  return v;
}
__device__ __forceinline__ float wave_max(float v){
  #pragma unroll
  for (int o=32;o>0;o>>=1) v = fmaxf(v, __shfl_down(v,o));
  return v;
}
// monotone float<->uint encoding for atomic max (init 0 < any encoded real value)
__device__ __forceinline__ unsigned encmax(float f){
  union{float f; unsigned u;} x; x.f = f;
  return (x.u & 0x80000000u) ? ~x.u : (x.u | 0x80000000u);
}
__device__ __forceinline__ float decmax(unsigned e){
  union{unsigned u; float f;} x;
  x.u = (e & 0x80000000u) ? (e & 0x7fffffffu) : ~e;
  return x.f;
}

// ---------------- embed: per-file linear + transpose + PE(F,S) ----------------
__global__ __launch_bounds__(256) void k_embed(const float* __restrict__ x,
    const float* __restrict__ lw, const float* __restrict__ lb,
    float* __restrict__ X)
{
  int idx = blockIdx.x*256 + threadIdx.x;      // (b*128+f)*256+s
  int s = idx & 255;
  int f = (idx >> 8) & 127;
  int b = idx >> 15;
  const float* xr = x + ((long)(b*256 + s))*2048 + f*16;
  const float* wr = lw + f*16;
  float acc = lb[f];
  #pragma unroll
  for (int c=0;c<16;c++) acc = fmaf(xr[c], wr[c], acc);
  int i = s >> 1;
  float dv = expf((float)(2*i) * (-9.210340371976184f/256.0f));
  float ang = (float)f * dv;
  acc += (s & 1) ? cosf(ang) : sinf(ang);
  X[idx] = acc;
}

// ---------------- LDS-tiled transpose [B,128,256]->[B,256,128] + PE(S,F) ----------------
__global__ __launch_bounds__(256) void k_transpose_pe(const float* __restrict__ X,
    float* __restrict__ Y)
{
  __shared__ float t[32][33];
  int b = blockIdx.z;
  int s0 = blockIdx.y*32, f0 = blockIdx.x*32;
  int tx = threadIdx.x & 31, ty = threadIdx.x >> 5;
  const float* Xp = X + ((long)b*128 + f0)*256 + s0;
  #pragma unroll
  for (int i=0;i<4;i++) t[ty+i*8][tx] = Xp[(long)(ty+i*8)*256 + tx];
  __syncthreads();
  int f = f0 + tx;
  int iD = f >> 1;
  float dv = expf((float)(2*iD) * (-9.210340371976184f/128.0f));
  float* Yp = Y + ((long)b*256 + s0)*128 + f0;
  #pragma unroll
  for (int i=0;i<4;i++){
    int s = s0 + ty + i*8;
    float ang = (float)s * dv;
    float pe = (f & 1) ? cosf(ang) : sinf(ang);
    Yp[(long)(ty+i*8)*128 + tx] = t[tx][ty+i*8] + pe;
  }
}

// ---------------- layernorm: fp32 in -> bf16 out ----------------
__global__ __launch_bounds__(256) void k_ln(const float* __restrict__ X,
    const float* __restrict__ w, const float* __restrict__ b,
    unsigned short* __restrict__ Y, int R, int D)
{
  int row = blockIdx.x*4 + (threadIdx.x >> 6);
  int lane = threadIdx.x & 63;
  if (row >= R) return;
  const float* xr = X + (long)row*D;
  float sum=0.f, sq=0.f;
  for (int i=lane;i<D;i+=64){ float v=xr[i]; sum+=v; sq+=v*v; }
  sum = wave_sum(sum); sq = wave_sum(sq);
  sum = __shfl(sum,0); sq = __shfl(sq,0);
  float mu = sum/(float)D;
  float var = sq/(float)D - mu*mu;
  float inv = rsqrtf(var + 1e-5f);
  unsigned short* yr = Y + (long)row*D;
  for (int i=lane;i<D;i+=64) yr[i] = f2b((xr[i]-mu)*inv*w[i] + b[i]);
}

// ---------------- merged weight transpose-convert ----------------
struct WTJobs {
  const float* src[12];
  unsigned short* dst[12];
  int K[12]; int N[12];
  long lstr[12];
};
__global__ __launch_bounds__(256) void k_wtall(WTJobs jt)
{
  __shared__ float t[32][33];
  int j = blockIdx.y;
  int K = jt.K[j], N = jt.N[j];
  int nx = N >> 5, ny = K >> 5;
  if ((int)blockIdx.x >= nx*ny) return;
  int nb = ((int)blockIdx.x % nx)*32, kb = ((int)blockIdx.x / nx)*32;
  int l = blockIdx.z;
  const float* Wp = jt.src[j] + (long)l*K*N;
  unsigned short* Tp = jt.dst[j] + (long)l*jt.lstr[j];
  int tx = threadIdx.x & 31, ty = threadIdx.x >> 5;
  #pragma unroll
  for (int i=0;i<4;i++) t[ty+i*8][tx] = Wp[(long)(kb+ty+i*8)*N + nb+tx];
  __syncthreads();
  #pragma unroll
  for (int i=0;i<4;i++) Tp[(long)(nb+ty+i*8)*K + kb+tx] = f2b(t[tx][ty+i*8]);
}

// ---------------- proj convert + pad ----------------
__global__ __launch_bounds__(256) void k_projconv(const float* __restrict__ proj,
    unsigned short* __restrict__ pb, int M, int Mp, int dh, long total)
{
  long idx = (long)blockIdx.x*256 + threadIdx.x;
  if (idx >= total) return;
  int c = (int)(idx % dh);
  long t = idx / dh;
  int m = (int)(t % Mp);
  int l = (int)(t / Mp);
  pb[idx] = (m < M) ? f2b(proj[((long)l*M + m)*dh + c]) : (unsigned short)0;
}

// ---------------- generic MFMA GEMM (T14-pipelined staging, TM=128 or 64 row tile) ----------
// C[R,NC] = alpha * A*B (+bias)(+gelu)(+res). K multiple of 32.
// EXPB: B is bf16 DD; staged as ratio*(exp(b-diag[k]-stab)+eps), 0 for c>=Mvalid (TM=128 only)
// MAXM==1: global atomic max; KSUM: per-column sums; DIAGM: fused FAVOR diag (TM=128 only)
// TM==64: 4 waves each own 64 rows x 32 cols (acc[4][2]); requires !A_CM, plain-B, no extras.
// Scatter-staged LDS tiles (A_CM / EXPB) use a col8 XOR swizzle to break 16-way bank conflicts.
template<bool A_CM, bool B_CM, int EPI, bool OUT_BF16, bool EXPB, int MAXM, bool KSUM,
         int DIAGM, int TM>
__global__ __launch_bounds__(256) void k_mgemm(
    const void* __restrict__ A, const void* __restrict__ B, void* __restrict__ C,
    const float* __restrict__ bias, const float* __restrict__ res,
    const float* __restrict__ ediag, const unsigned* __restrict__ estab,
    unsigned* __restrict__ maxu, float* __restrict__ ksumio,
    float* __restrict__ diagp, float dnn, int nseq, int diagH,
    float ratio, float eps, int Mvalid,
    float alpha, int H, int R, int NC, int K,
    long Ab, long Ah, long lda,
    long Bb, long Bh, long ldb,
    long Cb, long Ch, long ldc)
{
  constexpr int CF  = (TM==128) ? 4 : 2;      // col frags per wave
  constexpr int AIT = (TM==128) ? 2 : 1;      // A staging iterations
  __shared__ unsigned short Asm[TM][40];
  __shared__ unsigned short Bsm[128][40];
  __shared__ float sred[4];
  __shared__ float ks_lds[KSUM?16:1][KSUM?132:1];
  __shared__ float dg2[DIAGM==1?128:1][DIAGM==1?2:1];
  const int tid = threadIdx.x;
  const int bz = blockIdx.z;
  const int b = bz / H, h = bz - b*H;
  const unsigned short* Ap16 = (const unsigned short*)A + (long)b*Ab + (long)h*Ah;
  const unsigned short* Bp16 = (const unsigned short*)B + (long)b*Bb + (long)h*Bh;
  const int r0 = blockIdx.y*TM, c0 = blockIdx.x*128;
  const int wid = tid>>6, lane = tid&63;
  const int wr = wid>>1, wc = wid&1;
  const int lr = lane&15, lg = lane>>4;
  const int WRO = (TM==128) ? wr*64 : 0;                 // wave row offset
  const int WCO = (TM==128) ? wc*64 : wid*32;            // wave col offset
  float stabB = 0.f;
  if (EXPB) stabB = decmax(estab[0]);
  float kpart[KSUM?8:1] = {};
  f32x4 acc[4][CF] = {};

  // T14 prefetch registers + helpers (issue-early / write-late)
  u16x8 pA[AIT], pB[2];
  float pDg[2];
  auto loadA = [&](int k0){
    if constexpr (!A_CM){
      #pragma unroll
      for (int it=0; it<AIT; ++it){
        int idx = tid + it*256;
        int r = idx>>2, kq = (idx&3)*8;
        pA[it] = *reinterpret_cast<const u16x8*>(Ap16 + (long)(r0+r)*lda + (k0+kq));
      }
    } else {
      #pragma unroll
      for (int it=0; it<AIT; ++it){
        int idx = tid + it*256;
        int k = idx>>4, rq = (idx&15)*8;
        u16x8 v = {};
        if (r0+rq < R) v = *reinterpret_cast<const u16x8*>(Ap16 + (long)(k0+k)*lda + (r0+rq));
        pA[it] = v;
      }
    }
  };
  auto writeA = [&](){
    if constexpr (!A_CM){
      #pragma unroll
      for (int it=0; it<AIT; ++it){
        int idx = tid + it*256;
        int r = idx>>2, kq = (idx&3)*8;
        *reinterpret_cast<u16x8*>(&Asm[r][kq]) = pA[it];
      }
    } else {
      #pragma unroll
      for (int it=0; it<AIT; ++it){
        int idx = tid + it*256;
        int k = idx>>4, rq = (idx&15)*8;
        #pragma unroll
        for (int i=0;i<8;i++){
          int rr = rq + i;
          int sc = (k&7) | ((((k>>3) ^ ((rr>>3)&3)))<<3);   // col8 XOR swizzle
          Asm[rr][sc] = pA[it][i];
        }
      }
    }
  };
  auto loadB = [&](int k0){
    if constexpr (EXPB){
      #pragma unroll
      for (int it=0; it<2; ++it){
        int idx = tid + it*256;
        int k = idx>>4, cq = (idx&15)*8;
        pDg[it] = ediag[(long)bz*K + (k0+k)];
        u16x8 v = {};
        if (c0+cq < NC) v = *reinterpret_cast<const u16x8*>(Bp16 + (long)(k0+k)*ldb + (c0+cq));
        pB[it] = v;
      }
    } else if constexpr (B_CM){
      #pragma unroll
      for (int it=0; it<2; ++it){
        int idx = tid + it*256;
        int c = idx>>2, kq = (idx&3)*8;
        u16x8 v = {};
        if (c0+c < NC) v = *reinterpret_cast<const u16x8*>(Bp16 + (long)(c0+c)*ldb + (k0+kq));
        pB[it] = v;
      }
    } else {
      #pragma unroll
      for (int it=0; it<2; ++it){
        int idx = tid + it*256;
        int k = idx>>4, cq = (idx&15)*8;
        u16x8 v = {};
        if (c0+cq < NC) v = *reinterpret_cast<const u16x8*>(Bp16 + (long)(k0+k)*ldb + (c0+cq));
        pB[it] = v;
      }
    }
  };
  auto writeB = [&](int k0){
    if constexpr (EXPB){
      #pragma unroll
      for (int it=0; it<2; ++it){
        int idx = tid + it*256;
        int k = idx>>4, cq = (idx&15)*8;
        bool inb = (c0+cq < NC);
        #pragma unroll
        for (int i=0;i<8;i++){
          int c = c0+cq+i;
          float v = (c < Mvalid && inb) ? ratio*(expf(b2f(pB[it][i])-pDg[it]-stabB)+eps) : 0.0f;
          int rr = cq + i;
          int sc = (k&7) | ((((k>>3) ^ ((rr>>3)&3)))<<3);   // col8 XOR swizzle
          Bsm[rr][sc] = f2b(v);
          if (KSUM) kpart[i] += v;
        }
      }
    } else if constexpr (B_CM){
      #pragma unroll
      for (int it=0; it<2; ++it){
        int idx = tid + it*256;
        int c = idx>>2, kq = (idx&3)*8;
        *reinterpret_cast<u16x8*>(&Bsm[c][kq]) = pB[it];
      }
    } else {
      #pragma unroll
      for (int it=0; it<2; ++it){
        int idx = tid + it*256;
        int k = idx>>4, cq = (idx&15)*8;
        #pragma unroll
        for (int i=0;i<8;i++) Bsm[cq+i][k] = pB[it][i];
      }
    }
  };

  loadA(0); loadB(0);
  for (int k0=0; k0<K; k0+=32){
    writeA(); writeB(k0);
    __syncthreads();
    if (k0+32 < K){ loadA(k0+32); loadB(k0+32); }   // issue next tile early
    bf16x8 af[4], bfr[CF];
    #pragma unroll
    for (int m=0;m<4;m++){
      int arow = WRO + m*16 + lr;
      int acol8 = A_CM ? (lg ^ ((arow>>3)&3)) : lg;
      af[m] = *reinterpret_cast<const bf16x8*>(&Asm[arow][acol8*8]);
    }
    #pragma unroll
    for (int n=0;n<CF;n++){
      int brow = WCO + n*16 + lr;
      int bcol8 = EXPB ? (lg ^ ((brow>>3)&3)) : lg;
      bfr[n] = *reinterpret_cast<const bf16x8*>(&Bsm[brow][bcol8*8]);
    }
    #pragma unroll
    for (int m=0;m<4;m++)
      #pragma unroll
      for (int n=0;n<CF;n++)
        acc[m][n] = __builtin_amdgcn_mfma_f32_16x16x32_bf16(af[m], bfr[n], acc[m][n], 0, 0, 0);
    __syncthreads();
  }

  if constexpr (MAXM==1){
    float mx = -INFINITY;
    #pragma unroll
    for (int m=0;m<4;m++)
      #pragma unroll
      for (int n=0;n<CF;n++)
        #pragma unroll
        for (int e=0;e<4;e++) mx = fmaxf(mx, acc[m][n][e]);
    mx *= alpha;
    mx = wave_max(mx);
    if (lane==0) sred[wid]=mx;
    __syncthreads();
    if (tid==0) atomicMax(maxu, encmax(fmaxf(fmaxf(sred[0],sred[1]),fmaxf(sred[2],sred[3]))));
  }
  if constexpr (KSUM){
    #pragma unroll
    for (int j=0;j<8;j++) ks_lds[tid>>4][(tid&15)*8+j] = kpart[j];
    __syncthreads();
    if (tid < 128){
      float s = 0.f;
      #pragma unroll
      for (int g=0;g<16;g++) s += ks_lds[g][tid];
      int gc = c0 + tid;
      if (gc < NC) ksumio[(long)bz*NC + gc] = s;
    }
  }

  float* Cf = (float*)C;
  unsigned short* Cb16 = (unsigned short*)C;
  const long coff = (long)b*Cb + (long)h*Ch;
  #pragma unroll
  for (int m=0;m<4;m++){
    #pragma unroll
    for (int n=0;n<CF;n++){
      #pragma unroll
      for (int e=0;e<4;e++){
        int r = WRO + m*16 + lg*4 + e;
        int c = WCO + n*16 + lr;
        int gr = r0 + r, gc = c0 + c;
        if (gr < R && gc < NC){
          float v = acc[m][n][e] * alpha;
          if (EPI >= 2) v += bias[gc];
          if (EPI == 2) v = gelu_tanh(v);
          if (EPI == 3) v += res[(long)gr*ldc + gc];
          long o = coff + (long)gr*ldc + gc;
          if (OUT_BF16) Cb16[o] = f2b(v); else Cf[o] = v;
        }
      }
    }
  }

  // ---- fused FAVOR diag (K/Q segments) + REDU init (TM=128 only)
  if constexpr (DIAGM>0){
    if (bz == 0 && blockIdx.x == 0 && blockIdx.y == 0 && tid == 0) maxu[0] = 0u;
    if (bz < 2){
      const long soff = (long)bz * (long)R * diagH;
      #pragma unroll
      for (int m=0;m<4;m++)
        #pragma unroll
        for (int e=0;e<4;e++){
          int r = WRO + m*16 + lg*4 + e;
          float s = 0.f;
          #pragma unroll
          for (int nn=0;nn<CF;nn++) s = fmaf(acc[m][nn][e], acc[m][nn][e], s);
          #pragma unroll
          for (int o=1;o<16;o<<=1) s += __shfl_xor(s, o);
          if (lr==0){
            if constexpr (DIAGM==2){
              int gr = r0 + r;
              int bb = gr / nseq, ni = gr - bb*nseq;
              int hh = (int)blockIdx.x*2 + wc;
              diagp[soff + ((long)bb*diagH + hh)*nseq + ni] = dnn*s;
            } else {
              dg2[r][wc] = s;
            }
          }
        }
      if constexpr (DIAGM==1){
        __syncthreads();
        if (tid < 128){
          int gr = r0 + tid;
          int bb = gr / nseq, ni = gr - bb*nseq;
          int hh = (int)blockIdx.x;
          diagp[soff + ((long)bb*diagH + hh)*nseq + ni] = dnn*(dg2[tid][0] + dg2[tid][1]);
        }
      }
    }
  }
}

// ---------------- fused Q-side v8r: Q in regs, split P/C LDS buffers, 2 barriers/chunk ----
// Pass 2 iterates chunks in REVERSE so the proj chunk left resident from pass 1 is reused
// (saves the inter-pass re-stage + barrier). 8 waves/block, grid (bh, ny) XCD pairing.
template<int DH, int MP, int MM, int NCH, int NOUT>
__global__ __launch_bounds__(512) void k_qout(
    const unsigned short* __restrict__ Qb,   // [rows][I], head offset h*DH
    const unsigned short* __restrict__ proj, // [MP][DH] bf16 (pad rows zero)
    const unsigned short* __restrict__ CTXT, // per bh: [DH][MP]
    const float* __restrict__ diagq,         // [bh*n]
    const float* __restrict__ ksum,          // [bh*MP]
    unsigned short* __restrict__ out,        // [rows][I]
    float dn, float ratio, float eps,
    int H, int n, int I)
{
  constexpr int QP = DH + 8;
  constexpr int NST = DH/32;                       // k-frags for dd
  constexpr int NQS = (64*(DH/8) + 511)/512;       // proj staging iters
  constexpr int NCS = (DH*8 + 511)/512;            // CTXT staging iters
  __shared__ unsigned short Pb[64][QP];            // proj chunk
  __shared__ unsigned short Cb[DH][72];            // CTXT chunk
  __shared__ unsigned short qp[64][72];
  __shared__ float ks_all[MP];
  __shared__ float diag_lds[64], rmax4[4][64], qs4[4][64], dinv_lds[64];
  const int tid = threadIdx.x;
  const int bz = blockIdx.x;               // head on x: same-bz blocks share an XCD
  const int b = bz / H, h = bz - b*H;
  const int ni0 = blockIdx.y*64;
  const int wid = tid>>6, lane = tid&63;
  const int wr = wid>>2, wc = wid&3;
  const int lr = lane&15, lg = lane>>4;
  const long ctxoff = (long)bz*DH*MP;

  u16x8 rP[NQS], rC[NCS];
  auto ldP = [&](int mc){
    #pragma unroll
    for (int it=0; it<NQS; ++it){
      int idx = tid + it*512;
      int c = idx/(DH/8), seg = idx%(DH/8);
      int mg = mc*64 + c;
      rP[it] = (mg < MP) ? *reinterpret_cast<const u16x8*>(proj + (long)mg*DH + seg*8) : u16x8{};
    }
  };
  auto stP = [&](){
    #pragma unroll
    for (int it=0; it<NQS; ++it){
      int idx = tid + it*512;
      int c = idx/(DH/8), seg = idx%(DH/8);
      *reinterpret_cast<u16x8*>(&Pb[c][seg*8]) = rP[it];
    }
  };
  auto ldC = [&](int mc){
    #pragma unroll
    for (int it=0; it<NCS; ++it){
      int idx = tid + it*512;
      int c = idx>>3, kseg = idx&7;
      int kg = mc*64 + kseg*8;
      rC[it] = (kg < MP) ? *reinterpret_cast<const u16x8*>(CTXT + ctxoff + (long)c*MP + kg) : u16x8{};
    }
  };
  auto stC = [&](){
    #pragma unroll
    for (int it=0; it<NCS; ++it){
      int idx = tid + it*512;
      int c = idx>>3, kseg = idx&7;
      *reinterpret_cast<u16x8*>(&Cb[c][kseg*8]) = rC[it];
    }
  };

  // Q fragments -> registers (rows wr*32+m*16+lr fixed per thread)
  const unsigned short* Qp = Qb + ((long)(b*n + ni0))*I + h*DH;
  bf16x8 aq[2][NST];
  #pragma unroll
  for (int m=0;m<2;m++){
    int qrow = wr*32 + m*16 + lr;
    #pragma unroll
    for (int ks=0;ks<NST;ks++)
      aq[m][ks] = *reinterpret_cast<const bf16x8*>(Qp + (long)qrow*I + ks*32 + lg*8);
  }
  for (int i=tid;i<MP;i+=512) ks_all[i] = ksum[(long)bz*MP + i];
  if (tid < 64) diag_lds[tid] = diagq[(long)bz*n + ni0 + tid];
  ldP(0);
  stP();
  __syncthreads();   // diag, ks_all, Pb(proj 0) ready

  // ---- pass 1: row max over all chunks (pipelined proj staging)
  float rmax[2][4];
  #pragma unroll
  for (int m=0;m<2;m++)
    #pragma unroll
    for (int e=0;e<4;e++) rmax[m][e] = -INFINITY;
  for (int mc=0; mc<NCH; ++mc){
    if (mc+1 < NCH) ldP(mc+1);
    f32x4 dacc[2] = {};
    __builtin_amdgcn_s_setprio(1);
    #pragma unroll
    for (int ks=0; ks<NST; ++ks){
      bf16x8 bf_ = *reinterpret_cast<const bf16x8*>(&Pb[wc*16+lr][ks*32 + lg*8]);
      #pragma unroll
      for (int m=0;m<2;m++)
        dacc[m] = __builtin_amdgcn_mfma_f32_16x16x32_bf16(aq[m][ks], bf_, dacc[m], 0, 0, 0);
    }
    __builtin_amdgcn_s_setprio(0);
    {
      int col = mc*64 + wc*16 + lr;
      if (col < MM){
        #pragma unroll
        for (int m=0;m<2;m++)
          #pragma unroll
          for (int e=0;e<4;e++) rmax[m][e] = fmaxf(rmax[m][e], dacc[m][e]*dn);
      }
    }
    __syncthreads();
    if (mc+1 < NCH){ stP(); __syncthreads(); }
  }
  #pragma unroll
  for (int m=0;m<2;m++)
    #pragma unroll
    for (int e=0;e<4;e++){
      #pragma unroll
      for (int o=1;o<16;o<<=1) rmax[m][e] = fmaxf(rmax[m][e], __shfl_xor(rmax[m][e], o));
      if (lr==0) rmax4[wc][wr*32+m*16+lg*4+e] = rmax[m][e];
    }
  __syncthreads();
  if (tid < 64)
    rmax4[0][tid] = fmaxf(fmaxf(rmax4[0][tid], rmax4[1][tid]),
                          fmaxf(rmax4[2][tid], rmax4[3][tid]));
  __syncthreads();   // rmax ready; Pb still holds chunk NCH-1 from pass 1

  // ---- pass 2 (REVERSE order): dd -> exp -> qp; PV; 2 barriers per chunk
  float qsum[2][4] = {};
  f32x4 oacc[2][NOUT] = {};
  for (int mc=NCH-1; mc>=0; --mc){
    ldC(mc);
    f32x4 dacc[2] = {};
    __builtin_amdgcn_s_setprio(1);
    #pragma unroll
    for (int ks=0; ks<NST; ++ks){
      bf16x8 bf_ = *reinterpret_cast<const bf16x8*>(&Pb[wc*16+lr][ks*32 + lg*8]);
      #pragma unroll
      for (int m=0;m<2;m++)
        dacc[m] = __builtin_amdgcn_mfma_f32_16x16x32_bf16(aq[m][ks], bf_, dacc[m], 0, 0, 0);
    }
    __builtin_amdgcn_s_setprio(0);
    // exp -> qp LDS (+ dinv partials)
    {
      int lc = wc*16 + lr;
      int col = mc*64 + lc;
      bool valid = (col < MM);
      float kv = valid ? ks_all[col] : 0.f;
      #pragma unroll
      for (int m=0;m<2;m++)
        #pragma unroll
        for (int e=0;e<4;e++){
          int row = wr*32+m*16+lg*4+e;
          float v = 0.f;
          if (valid){
            v = ratio*(expf(dacc[m][e]*dn - diag_lds[row] - rmax4[0][row]) + eps);
            qsum[m][e] = fmaf(v, kv, qsum[m][e]);
          }
          qp[row][lc] = f2b(v);
        }
    }
    stC();                       // write CTXT chunk into Cb (disjoint from Pb)
    if (mc > 0) ldP(mc-1);       // issue next (previous-index) proj loads
    __syncthreads();             // A: qp + Cb ready; Pb reads done
    __builtin_amdgcn_s_setprio(1);
    #pragma unroll
    for (int ks=0; ks<2; ++ks){
      bf16x8 af[2];
      #pragma unroll
      for (int m=0;m<2;m++) af[m] = *reinterpret_cast<const bf16x8*>(&qp[wr*32+m*16+lr][ks*32+lg*8]);
      #pragma unroll
      for (int nn=0;nn<NOUT;nn++){
        bf16x8 bf_ = *reinterpret_cast<const bf16x8*>(&Cb[wc*(DH/4)+nn*16+lr][ks*32 + lg*8]);
        #pragma unroll
        for (int m=0;m<2;m++)
          oacc[m][nn] = __builtin_amdgcn_mfma_f32_16x16x32_bf16(af[m], bf_, oacc[m][nn], 0, 0, 0);
      }
    }
    __builtin_amdgcn_s_setprio(0);
    if (mc > 0) stP();           // write next proj into Pb (PV doesn't touch Pb)
    __syncthreads();             // B: Pb ready for next dd; Cb/qp reads done
  }

  #pragma unroll
  for (int m=0;m<2;m++)
    #pragma unroll
    for (int e=0;e<4;e++){
      float s = qsum[m][e];
      #pragma unroll
      for (int o=1;o<16;o<<=1) s += __shfl_xor(s, o);
      if (lr==0) qs4[wc][wr*32+m*16+lg*4+e] = s;
    }
  __syncthreads();
  if (tid < 64) dinv_lds[tid] = 1.0f/(qs4[0][tid] + qs4[1][tid] + qs4[2][tid] + qs4[3][tid]);
  __syncthreads();

  unsigned short* Op = out + ((long)(b*n + ni0))*I + h*DH;
  #pragma unroll
  for (int m=0;m<2;m++)
    #pragma unroll
    for (int e=0;e<4;e++){
      int row = wr*32+m*16+lg*4+e;
      float di = dinv_lds[row];
      #pragma unroll
      for (int nn=0;nn<NOUT;nn++){
        int c = wc*(DH/4)+nn*16+lr;
        Op[(long)row*I + c] = f2b(oacc[m][nn][e]*di);
      }
    }
}

// ---------------- final mean over s ----------------
__global__ __launch_bounds__(256) void k_mean(const float* __restrict__ X,
    float* __restrict__ out)
{
  int idx = blockIdx.x*256 + threadIdx.x;   // b*128+f
  int f = idx & 127, b = idx >> 7;
  const float* p = X + (long)b*256*128 + f;
  float s = 0.f;
  for (int i=0;i<256;i++) s += p[i*128];
  out[idx] = s*(1.0f/256.0f);
}

// ---------------- host-side stage driver ----------------
struct StageP {
  const float *ln1w,*ln1b,*wob,*ln2w,*ln2b,*f1b,*f2b;
  const unsigned short *wkqvT,*woT,*f1T,*f2T,*projb;
  int n, D, H, dh, I, M, Mp;
};

template<int DH, int MP, int MM, int NCH, int NOUT, int DGM>
static void run_stage(const StageP& P, float* X, unsigned short* LNb,
    unsigned short* KQVb, unsigned short* DDk, unsigned short* CTXT,
    unsigned short* ATTNb, unsigned short* FFHb,
    float* KPSUM, float* DIAG, unsigned* REDU,
    hipStream_t stream)
{
  const int B = 64;
  const int rows = B*P.n;
  const int bh = B*P.H;
  const int bhn = bh*P.n;
  const float dn = powf((float)P.dh, -0.25f);
  const float dnn = 0.5f*dn*dn;
  const float ratio = 1.0f/sqrtf((float)P.M);
  const float eps = 1e-4f;

  const unsigned short* Kb = KQVb;
  const unsigned short* Qb = KQVb + (long)rows*P.I;
  const unsigned short* Vb = KQVb + 2L*rows*P.I;
  const float* DIAGK = DIAG;
  const float* DIAGQ = DIAG + bhn;

  for (int l=0;l<4;l++){
    const float* ln1w = P.ln1w + (long)l*P.D;
    const float* ln1b = P.ln1b + (long)l*P.D;
    const float* wob  = P.wob  + (long)l*P.D;
    const float* ln2w = P.ln2w + (long)l*P.D;
    const float* ln2b = P.ln2b + (long)l*P.D;
    const float* f1b  = P.f1b  + (long)l*4*P.D;
    const float* f2b_ = P.f2b  + (long)l*P.D;
    const unsigned short* wkqvT = P.wkqvT + (long)l*3*P.D*P.I;
    const unsigned short* woT = P.woT + (long)l*P.I*P.D;
    const unsigned short* f1T = P.f1T + (long)l*P.D*4*P.D;
    const unsigned short* f2T = P.f2T + (long)l*4*P.D*P.D;
    const unsigned short* pjb = P.projb + (long)l*P.Mp*P.dh;

    // LN1 (once) -> LNb
    k_ln<<<dim3((rows+3)/4),dim3(256),0,stream>>>(X, ln1w, ln1b, LNb, rows, P.D);
    // K,Q,V projection + diag epilogue + REDU init
    dim3 gq(P.I/128, rows/128, 3);
    k_mgemm<false,true,0,true,false,0,false,DGM,128><<<gq,dim3(256),0,stream>>>(
        LNb, wkqvT, KQVb, nullptr,nullptr, nullptr,nullptr, REDU, nullptr,
        DIAG, dnn, P.n, P.H,
        0,0,0, 1.f, 1, rows, P.I, P.D,
        0,0,(long)P.D,
        (long)P.I*P.D,0,(long)P.D,
        (long)rows*P.I,0,(long)P.I);
    // dd_k -> DDk (bf16), fused global max
    dim3 gdd((P.Mp+127)/128, P.n/128, bh);
    k_mgemm<false,true,0,true,false,1,false,0,128><<<gdd,dim3(256),0,stream>>>(
        Kb, pjb, DDk, nullptr,nullptr, nullptr,nullptr, REDU, nullptr,
        nullptr, 0.f, 0, 0,
        0,0,0, dn, P.H, P.n, P.Mp, P.dh,
        (long)P.n*P.I, (long)P.dh, (long)P.I,
        0, 0, (long)P.dh,
        (long)P.H*P.n*P.Mp, (long)P.n*P.Mp, (long)P.Mp);
    // CTXT = V^T @ kp with exp fused on B-stage + fused kpsum
    dim3 gctx((P.Mp+127)/128, (P.dh+127)/128, bh);
    k_mgemm<true,false,0,true,true,0,true,0,128><<<gctx,dim3(256),0,stream>>>(
        Vb, DDk, CTXT, nullptr,nullptr, DIAGK, REDU, nullptr, KPSUM,
        nullptr, 0.f, 0, 0,
        ratio, eps, P.M,
        1.f, P.H, P.dh, P.Mp, P.n,
        (long)P.n*P.I, (long)P.dh, (long)P.I,
        (long)P.H*P.n*P.Mp, (long)P.n*P.Mp, (long)P.Mp,
        (long)P.H*P.dh*P.Mp, (long)P.dh*P.Mp, (long)P.Mp);
    // fused Q side: 8 waves/block; grid (bh, ny) so same-head blocks share an XCD's L2
    dim3 gqo(bh, P.n/64, 1);
    k_qout<DH,MP,MM,NCH,NOUT><<<gqo,dim3(512),0,stream>>>(
        Qb, pjb, CTXT, DIAGQ, KPSUM, ATTNb, dn, ratio, eps, P.H, P.n, P.I);
    // x = x + attn @ wo + wob  (TM=64)
    dim3 gwo(P.D/128, rows/64, 1);
    k_mgemm<false,true,3,false,false,0,false,0,64><<<gwo,dim3(256),0,stream>>>(
        ATTNb, woT, X, wob, X, nullptr,nullptr, nullptr,nullptr,
        nullptr, 0.f, 0, 0,
        0,0,0, 1.f, 1, rows, P.D, P.I, 0,0,(long)P.I, 0,0,(long)P.I, 0,0,(long)P.D);
    // LN2 (once) -> LNb
    k_ln<<<dim3((rows+3)/4),dim3(256),0,stream>>>(X, ln2w, ln2b, LNb, rows, P.D);
    // FF1 (gelu)
    dim3 gf1(4*P.D/128, rows/128, 1);
    k_mgemm<false,true,2,true,false,0,false,0,128><<<gf1,dim3(256),0,stream>>>(
        LNb, f1T, FFHb, f1b, nullptr, nullptr,nullptr, nullptr,nullptr,
        nullptr, 0.f, 0, 0,
        0,0,0, 1.f, 1, rows, 4*P.D, P.D, 0,0,(long)P.D, 0,0,(long)P.D, 0,0,(long)(4*P.D));
    // FF2 + residual (TM=64)
    dim3 gf2(P.D/128, rows/64, 1);
    k_mgemm<false,true,3,false,false,0,false,0,64><<<gf2,dim3(256),0,stream>>>(
        FFHb, f2T, X, f2b_, X, nullptr,nullptr, nullptr,nullptr,
        nullptr, 0.f, 0, 0,
        0,0,0, 1.f, 1, rows, P.D, 4*P.D, 0,0,(long)(4*P.D), 0,0,(long)(4*P.D), 0,0,(long)P.D);
  }
}

// ---------------- entry ----------------
extern "C" void kernel_launch(void* const* d_in, const int* in_sizes, int n_in,
                              void* d_out, int out_size, void* d_ws, size_t ws_size,
                              hipStream_t stream)
{
  const float* x     = (const float*)d_in[0];
  const float* lin_w = (const float*)d_in[1];
  const float* lin_b = (const float*)d_in[2];

  char* wsb = (char*)d_ws;
  size_t off = 0;
  auto alloc = [&](size_t bytes)->void*{ void* p = wsb + off; off += (bytes + 255) & ~(size_t)255; return p; };
  float* X     = (float*)alloc(8388608);
  float* X2    = (float*)alloc(8388608);
  unsigned short* LNb   = (unsigned short*)alloc(4194304);
  unsigned short* KQVb  = (unsigned short*)alloc(31457280);   // [K][Q][V] bf16
  unsigned short* DDk   = (unsigned short*)alloc(52428800);   // bf16 dd_k (aliased as FF hidden)
  unsigned short* CTXT  = (unsigned short*)alloc(52428800);
  unsigned short* ATTNb = (unsigned short*)alloc(10485760);
  unsigned short* WKQV1 = (unsigned short*)alloc(3932160);    // [L][3][I][D]
  unsigned short* WO1T  = (unsigned short*)alloc(1310720);
  unsigned short* F11T  = (unsigned short*)alloc(2097152);
  unsigned short* F21T  = (unsigned short*)alloc(2097152);
  unsigned short* WKQV2 = (unsigned short*)alloc(786432);
  unsigned short* WO2T  = (unsigned short*)alloc(262144);
  unsigned short* F12T  = (unsigned short*)alloc(524288);
  unsigned short* F22T  = (unsigned short*)alloc(524288);
  unsigned short* PJ1   = (unsigned short*)alloc(655360);
  unsigned short* PJ2   = (unsigned short*)alloc(147456);
  float* KPSUM = (float*)alloc(819200);
  float* DIAG  = (float*)alloc(524288);
  unsigned* REDU = (unsigned*)alloc(256);
  unsigned short* FFHb = DDk;   // FF hidden aliases DDk (dead during FF)
  if (ws_size < off) return;

  // ---- merged weight conversions ----
  WTJobs jt;
  jt.src[0]=(const float*)d_in[6];  jt.dst[0]=WKQV1+0L*640*256;  jt.K[0]=256; jt.N[0]=640;  jt.lstr[0]=3L*640*256;
  jt.src[1]=(const float*)d_in[5];  jt.dst[1]=WKQV1+1L*640*256;  jt.K[1]=256; jt.N[1]=640;  jt.lstr[1]=3L*640*256;
  jt.src[2]=(const float*)d_in[7];  jt.dst[2]=WKQV1+2L*640*256;  jt.K[2]=256; jt.N[2]=640;  jt.lstr[2]=3L*640*256;
  jt.src[3]=(const float*)d_in[8];  jt.dst[3]=WO1T;              jt.K[3]=640; jt.N[3]=256;  jt.lstr[3]=640L*256;
  jt.src[4]=(const float*)d_in[12]; jt.dst[4]=F11T;              jt.K[4]=256; jt.N[4]=1024; jt.lstr[4]=1024L*256;
  jt.src[5]=(const float*)d_in[14]; jt.dst[5]=F21T;              jt.K[5]=1024;jt.N[5]=256;  jt.lstr[5]=1024L*256;
  jt.src[6]=(const float*)d_in[20]; jt.dst[6]=WKQV2+0L*256*128;  jt.K[6]=128; jt.N[6]=256;  jt.lstr[6]=3L*256*128;
  jt.src[7]=(const float*)d_in[19]; jt.dst[7]=WKQV2+1L*256*128;  jt.K[7]=128; jt.N[7]=256;  jt.lstr[7]=3L*256*128;
  jt.src[8]=(const float*)d_in[21]; jt.dst[8]=WKQV2+2L*256*128;  jt.K[8]=128; jt.N[8]=256;  jt.lstr[8]=3L*256*128;
  jt.src[9]=(const float*)d_in[22]; jt.dst[9]=WO2T;              jt.K[9]=256; jt.N[9]=128;  jt.lstr[9]=256L*128;
  jt.src[10]=(const float*)d_in[26];jt.dst[10]=F12T;             jt.K[10]=128;jt.N[10]=512; jt.lstr[10]=512L*128;
  jt.src[11]=(const float*)d_in[28];jt.dst[11]=F22T;             jt.K[11]=512;jt.N[11]=128; jt.lstr[11]=512L*128;
  k_wtall<<<dim3(256,12,4),dim3(256),0,stream>>>(jt);
  {
    long t1 = 4L*640*128;
    k_projconv<<<dim3((int)((t1+255)/256)),dim3(256),0,stream>>>((const float*)d_in[16], PJ1, 620, 640, 128, t1);
    long t2 = 4L*288*64;
    k_projconv<<<dim3((int)((t2+255)/256)),dim3(256),0,stream>>>((const float*)d_in[30], PJ2, 266, 288, 64, t2);
  }

  StageP T;
  T.ln1w=(const float*)d_in[3];  T.ln1b=(const float*)d_in[4];
  T.wob=(const float*)d_in[9];
  T.ln2w=(const float*)d_in[10]; T.ln2b=(const float*)d_in[11];
  T.f1b=(const float*)d_in[13];  T.f2b=(const float*)d_in[15];
  T.wkqvT=WKQV1; T.woT=WO1T; T.f1T=F11T; T.f2T=F21T; T.projb=PJ1;
  T.n=128; T.D=256; T.H=5; T.dh=128; T.I=640; T.M=620; T.Mp=640;

  StageP Ms;
  Ms.ln1w=(const float*)d_in[17]; Ms.ln1b=(const float*)d_in[18];
  Ms.wob=(const float*)d_in[23];
  Ms.ln2w=(const float*)d_in[24]; Ms.ln2b=(const float*)d_in[25];
  Ms.f1b=(const float*)d_in[27];  Ms.f2b=(const float*)d_in[29];
  Ms.wkqvT=WKQV2; Ms.woT=WO2T; Ms.f1T=F12T; Ms.f2T=F22T; Ms.projb=PJ2;
  Ms.n=256; Ms.D=128; Ms.H=4; Ms.dh=64; Ms.I=256; Ms.M=266; Ms.Mp=288;

  k_embed<<<dim3(8192),dim3(256),0,stream>>>(x, lin_w, lin_b, X);
  run_stage<128,640,620,10,2,1>(T, X, LNb, KQVb, DDk, CTXT, ATTNb, FFHb,
            KPSUM, DIAG, REDU, stream);
  k_transpose_pe<<<dim3(4,8,64),dim3(256),0,stream>>>(X, X2);
  run_stage<64,288,266,5,1,2>(Ms, X2, LNb, KQVb, DDk, CTXT, ATTNb, FFHb,
            KPSUM, DIAG, REDU, stream);
  k_mean<<<dim3(32),dim3(256),0,stream>>>(X2, (float*)d_out);
}

// Round 22
// 1812.333 us; speedup vs baseline: 1.0423x; 1.0423x over previous
//
#include <hip/hip_runtime.h>
#include <math.h>

using bf16x8 = __attribute__((ext_vector_type(8))) short;
using f32x4  = __attribute__((ext_vector_type(4))) float;
using u16x8  = __attribute__((ext_vector_type(8))) unsigned short;

__device__ __forceinline__ float b2f(unsigned short u){
  union{float f; unsigned int i;} x; x.i = ((unsigned int)u)<<16; return x.f;
}
__device__ __forceinline__ unsigned short f2b(float f){
  union{float f; unsigned int i;} x; x.f = f;
  unsigned int r = x.i + 0x7fffu + ((x.i>>16)&1u);
  return (unsigned short)(r>>16);
}
__device__ __forceinline__ float gelu_tanh(float x){
  float x3 = x*x*x;
  return 0.5f*x*(1.0f + tanhf(0.79788456080286535588f*(x + 0.044715f*x3)));
}
__device__ __forceinline__ float wave_sum(float v){
  #pragma unroll
  for (int o=32;o>0;o>>=1) v += __shfl_down(v,o);
  return v;
}
__device__ __forceinline__ float wave_max(float v){
  #pragma unroll
  for (int o=32;o>0;o>>=1) v = fmaxf(v, __shfl_down(v,o));
  return v;
}
// monotone float<->uint encoding for atomic max (init 0 < any encoded real value)
__device__ __forceinline__ unsigned encmax(float f){
  union{float f; unsigned u;} x; x.f = f;
  return (x.u & 0x80000000u) ? ~x.u : (x.u | 0x80000000u);
}
__device__ __forceinline__ float decmax(unsigned e){
  union{unsigned u; float f;} x;
  x.u = (e & 0x80000000u) ? (e & 0x7fffffffu) : ~e;
  return x.f;
}

// ---------------- embed: per-file linear + transpose + PE(F,S) ----------------
__global__ __launch_bounds__(256) void k_embed(const float* __restrict__ x,
    const float* __restrict__ lw, const float* __restrict__ lb,
    float* __restrict__ X)
{
  int idx = blockIdx.x*256 + threadIdx.x;      // (b*128+f)*256+s
  int s = idx & 255;
  int f = (idx >> 8) & 127;
  int b = idx >> 15;
  const float* xr = x + ((long)(b*256 + s))*2048 + f*16;
  const float* wr = lw + f*16;
  float acc = lb[f];
  #pragma unroll
  for (int c=0;c<16;c++) acc = fmaf(xr[c], wr[c], acc);
  int i = s >> 1;
  float dv = expf((float)(2*i) * (-9.210340371976184f/256.0f));
  float ang = (float)f * dv;
  acc += (s & 1) ? cosf(ang) : sinf(ang);
  X[idx] = acc;
}

// ---------------- LDS-tiled transpose [B,128,256]->[B,256,128] + PE(S,F) ----------------
__global__ __launch_bounds__(256) void k_transpose_pe(const float* __restrict__ X,
    float* __restrict__ Y)
{
  __shared__ float t[32][33];
  int b = blockIdx.z;
  int s0 = blockIdx.y*32, f0 = blockIdx.x*32;
  int tx = threadIdx.x & 31, ty = threadIdx.x >> 5;
  const float* Xp = X + ((long)b*128 + f0)*256 + s0;
  #pragma unroll
  for (int i=0;i<4;i++) t[ty+i*8][tx] = Xp[(long)(ty+i*8)*256 + tx];
  __syncthreads();
  int f = f0 + tx;
  int iD = f >> 1;
  float dv = expf((float)(2*iD) * (-9.210340371976184f/128.0f));
  float* Yp = Y + ((long)b*256 + s0)*128 + f0;
  #pragma unroll
  for (int i=0;i<4;i++){
    int s = s0 + ty + i*8;
    float ang = (float)s * dv;
    float pe = (f & 1) ? cosf(ang) : sinf(ang);
    Yp[(long)(ty+i*8)*128 + tx] = t[tx][ty+i*8] + pe;
  }
}

// ---------------- layernorm: fp32 in -> bf16 out ----------------
__global__ __launch_bounds__(256) void k_ln(const float* __restrict__ X,
    const float* __restrict__ w, const float* __restrict__ b,
    unsigned short* __restrict__ Y, int R, int D)
{
  int row = blockIdx.x*4 + (threadIdx.x >> 6);
  int lane = threadIdx.x & 63;
  if (row >= R) return;
  const float* xr = X + (long)row*D;
  float sum=0.f, sq=0.f;
  for (int i=lane;i<D;i+=64){ float v=xr[i]; sum+=v; sq+=v*v; }
  sum = wave_sum(sum); sq = wave_sum(sq);
  sum = __shfl(sum,0); sq = __shfl(sq,0);
  float mu = sum/(float)D;
  float var = sq/(float)D - mu*mu;
  float inv = rsqrtf(var + 1e-5f);
  unsigned short* yr = Y + (long)row*D;
  for (int i=lane;i<D;i+=64) yr[i] = f2b((xr[i]-mu)*inv*w[i] + b[i]);
}

// ---------------- merged weight transpose-convert ----------------
struct WTJobs {
  const float* src[12];
  unsigned short* dst[12];
  int K[12]; int N[12];
  long lstr[12];
};
__global__ __launch_bounds__(256) void k_wtall(WTJobs jt)
{
  __shared__ float t[32][33];
  int j = blockIdx.y;
  int K = jt.K[j], N = jt.N[j];
  int nx = N >> 5, ny = K >> 5;
  if ((int)blockIdx.x >= nx*ny) return;
  int nb = ((int)blockIdx.x % nx)*32, kb = ((int)blockIdx.x / nx)*32;
  int l = blockIdx.z;
  const float* Wp = jt.src[j] + (long)l*K*N;
  unsigned short* Tp = jt.dst[j] + (long)l*jt.lstr[j];
  int tx = threadIdx.x & 31, ty = threadIdx.x >> 5;
  #pragma unroll
  for (int i=0;i<4;i++) t[ty+i*8][tx] = Wp[(long)(kb+ty+i*8)*N + nb+tx];
  __syncthreads();
  #pragma unroll
  for (int i=0;i<4;i++) Tp[(long)(nb+ty+i*8)*K + kb+tx] = f2b(t[tx][ty+i*8]);
}

// ---------------- proj convert + pad ----------------
__global__ __launch_bounds__(256) void k_projconv(const float* __restrict__ proj,
    unsigned short* __restrict__ pb, int M, int Mp, int dh, long total)
{
  long idx = (long)blockIdx.x*256 + threadIdx.x;
  if (idx >= total) return;
  int c = (int)(idx % dh);
  long t = idx / dh;
  int m = (int)(t % Mp);
  int l = (int)(t / Mp);
  pb[idx] = (m < M) ? f2b(proj[((long)l*M + m)*dh + c]) : (unsigned short)0;
}

// ---------------- generic MFMA GEMM (T14-pipelined staging, TM=128 or 64 row tile) ----------
// C[R,NC] = alpha * A*B (+bias)(+gelu)(+res). K multiple of 32.
// EXPB: B is bf16 DD; staged as ratio*(exp(b-diag[k]-stab)+eps), 0 for c>=Mvalid (TM=128 only)
// MAXM==1: global atomic max; KSUM: per-column sums; DIAGM: fused FAVOR diag (TM=128 only)
// TM==64: 4 waves each own 64 rows x 32 cols (acc[4][2]); requires !A_CM, plain-B, no extras.
// Scatter-staged LDS tiles (A_CM / EXPB) use a col8 XOR swizzle to break 16-way bank conflicts.
template<bool A_CM, bool B_CM, int EPI, bool OUT_BF16, bool EXPB, int MAXM, bool KSUM,
         int DIAGM, int TM>
__global__ __launch_bounds__(256) void k_mgemm(
    const void* __restrict__ A, const void* __restrict__ B, void* __restrict__ C,
    const float* __restrict__ bias, const float* __restrict__ res,
    const float* __restrict__ ediag, const unsigned* __restrict__ estab,
    unsigned* __restrict__ maxu, float* __restrict__ ksumio,
    float* __restrict__ diagp, float dnn, int nseq, int diagH,
    float ratio, float eps, int Mvalid,
    float alpha, int H, int R, int NC, int K,
    long Ab, long Ah, long lda,
    long Bb, long Bh, long ldb,
    long Cb, long Ch, long ldc)
{
  constexpr int CF  = (TM==128) ? 4 : 2;      // col frags per wave
  constexpr int AIT = (TM==128) ? 2 : 1;      // A staging iterations
  __shared__ unsigned short Asm[TM][40];
  __shared__ unsigned short Bsm[128][40];
  __shared__ float sred[4];
  __shared__ float ks_lds[KSUM?16:1][KSUM?132:1];
  __shared__ float dg2[DIAGM==1?128:1][DIAGM==1?2:1];
  const int tid = threadIdx.x;
  const int bz = blockIdx.z;
  const int b = bz / H, h = bz - b*H;
  const unsigned short* Ap16 = (const unsigned short*)A + (long)b*Ab + (long)h*Ah;
  const unsigned short* Bp16 = (const unsigned short*)B + (long)b*Bb + (long)h*Bh;
  const int r0 = blockIdx.y*TM, c0 = blockIdx.x*128;
  const int wid = tid>>6, lane = tid&63;
  const int wr = wid>>1, wc = wid&1;
  const int lr = lane&15, lg = lane>>4;
  const int WRO = (TM==128) ? wr*64 : 0;                 // wave row offset
  const int WCO = (TM==128) ? wc*64 : wid*32;            // wave col offset
  float stabB = 0.f;
  if (EXPB) stabB = decmax(estab[0]);
  float kpart[KSUM?8:1] = {};
  f32x4 acc[4][CF] = {};

  // T14 prefetch registers + helpers (issue-early / write-late)
  u16x8 pA[AIT], pB[2];
  float pDg[2];
  auto loadA = [&](int k0){
    if constexpr (!A_CM){
      #pragma unroll
      for (int it=0; it<AIT; ++it){
        int idx = tid + it*256;
        int r = idx>>2, kq = (idx&3)*8;
        pA[it] = *reinterpret_cast<const u16x8*>(Ap16 + (long)(r0+r)*lda + (k0+kq));
      }
    } else {
      #pragma unroll
      for (int it=0; it<AIT; ++it){
        int idx = tid + it*256;
        int k = idx>>4, rq = (idx&15)*8;
        u16x8 v = {};
        if (r0+rq < R) v = *reinterpret_cast<const u16x8*>(Ap16 + (long)(k0+k)*lda + (r0+rq));
        pA[it] = v;
      }
    }
  };
  auto writeA = [&](){
    if constexpr (!A_CM){
      #pragma unroll
      for (int it=0; it<AIT; ++it){
        int idx = tid + it*256;
        int r = idx>>2, kq = (idx&3)*8;
        *reinterpret_cast<u16x8*>(&Asm[r][kq]) = pA[it];
      }
    } else {
      #pragma unroll
      for (int it=0; it<AIT; ++it){
        int idx = tid + it*256;
        int k = idx>>4, rq = (idx&15)*8;
        #pragma unroll
        for (int i=0;i<8;i++){
          int rr = rq + i;
          int sc = (k&7) | ((((k>>3) ^ ((rr>>3)&3)))<<3);   // col8 XOR swizzle
          Asm[rr][sc] = pA[it][i];
        }
      }
    }
  };
  auto loadB = [&](int k0){
    if constexpr (EXPB){
      #pragma unroll
      for (int it=0; it<2; ++it){
        int idx = tid + it*256;
        int k = idx>>4, cq = (idx&15)*8;
        pDg[it] = ediag[(long)bz*K + (k0+k)];
        u16x8 v = {};
        if (c0+cq < NC) v = *reinterpret_cast<const u16x8*>(Bp16 + (long)(k0+k)*ldb + (c0+cq));
        pB[it] = v;
      }
    } else if constexpr (B_CM){
      #pragma unroll
      for (int it=0; it<2; ++it){
        int idx = tid + it*256;
        int c = idx>>2, kq = (idx&3)*8;
        u16x8 v = {};
        if (c0+c < NC) v = *reinterpret_cast<const u16x8*>(Bp16 + (long)(c0+c)*ldb + (k0+kq));
        pB[it] = v;
      }
    } else {
      #pragma unroll
      for (int it=0; it<2; ++it){
        int idx = tid + it*256;
        int k = idx>>4, cq = (idx&15)*8;
        u16x8 v = {};
        if (c0+cq < NC) v = *reinterpret_cast<const u16x8*>(Bp16 + (long)(k0+k)*ldb + (c0+cq));
        pB[it] = v;
      }
    }
  };
  auto writeB = [&](int k0){
    if constexpr (EXPB){
      #pragma unroll
      for (int it=0; it<2; ++it){
        int idx = tid + it*256;
        int k = idx>>4, cq = (idx&15)*8;
        bool inb = (c0+cq < NC);
        #pragma unroll
        for (int i=0;i<8;i++){
          int c = c0+cq+i;
          float v = (c < Mvalid && inb) ? ratio*(expf(b2f(pB[it][i])-pDg[it]-stabB)+eps) : 0.0f;
          int rr = cq + i;
          int sc = (k&7) | ((((k>>3) ^ ((rr>>3)&3)))<<3);   // col8 XOR swizzle
          Bsm[rr][sc] = f2b(v);
          if (KSUM) kpart[i] += v;
        }
      }
    } else if constexpr (B_CM){
      #pragma unroll
      for (int it=0; it<2; ++it){
        int idx = tid + it*256;
        int c = idx>>2, kq = (idx&3)*8;
        *reinterpret_cast<u16x8*>(&Bsm[c][kq]) = pB[it];
      }
    } else {
      #pragma unroll
      for (int it=0; it<2; ++it){
        int idx = tid + it*256;
        int k = idx>>4, cq = (idx&15)*8;
        #pragma unroll
        for (int i=0;i<8;i++) Bsm[cq+i][k] = pB[it][i];
      }
    }
  };

  loadA(0); loadB(0);
  for (int k0=0; k0<K; k0+=32){
    writeA(); writeB(k0);
    __syncthreads();
    if (k0+32 < K){ loadA(k0+32); loadB(k0+32); }   // issue next tile early
    bf16x8 af[4], bfr[CF];
    #pragma unroll
    for (int m=0;m<4;m++){
      int arow = WRO + m*16 + lr;
      int acol8 = A_CM ? (lg ^ ((arow>>3)&3)) : lg;
      af[m] = *reinterpret_cast<const bf16x8*>(&Asm[arow][acol8*8]);
    }
    #pragma unroll
    for (int n=0;n<CF;n++){
      int brow = WCO + n*16 + lr;
      int bcol8 = EXPB ? (lg ^ ((brow>>3)&3)) : lg;
      bfr[n] = *reinterpret_cast<const bf16x8*>(&Bsm[brow][bcol8*8]);
    }
    #pragma unroll
    for (int m=0;m<4;m++)
      #pragma unroll
      for (int n=0;n<CF;n++)
        acc[m][n] = __builtin_amdgcn_mfma_f32_16x16x32_bf16(af[m], bfr[n], acc[m][n], 0, 0, 0);
    __syncthreads();
  }

  if constexpr (MAXM==1){
    float mx = -INFINITY;
    #pragma unroll
    for (int m=0;m<4;m++)
      #pragma unroll
      for (int n=0;n<CF;n++)
        #pragma unroll
        for (int e=0;e<4;e++) mx = fmaxf(mx, acc[m][n][e]);
    mx *= alpha;
    mx = wave_max(mx);
    if (lane==0) sred[wid]=mx;
    __syncthreads();
    if (tid==0) atomicMax(maxu, encmax(fmaxf(fmaxf(sred[0],sred[1]),fmaxf(sred[2],sred[3]))));
  }
  if constexpr (KSUM){
    #pragma unroll
    for (int j=0;j<8;j++) ks_lds[tid>>4][(tid&15)*8+j] = kpart[j];
    __syncthreads();
    if (tid < 128){
      float s = 0.f;
      #pragma unroll
      for (int g=0;g<16;g++) s += ks_lds[g][tid];
      int gc = c0 + tid;
      if (gc < NC) ksumio[(long)bz*NC + gc] = s;
    }
  }

  float* Cf = (float*)C;
  unsigned short* Cb16 = (unsigned short*)C;
  const long coff = (long)b*Cb + (long)h*Ch;
  #pragma unroll
  for (int m=0;m<4;m++){
    #pragma unroll
    for (int n=0;n<CF;n++){
      #pragma unroll
      for (int e=0;e<4;e++){
        int r = WRO + m*16 + lg*4 + e;
        int c = WCO + n*16 + lr;
        int gr = r0 + r, gc = c0 + c;
        if (gr < R && gc < NC){
          float v = acc[m][n][e] * alpha;
          if (EPI >= 2) v += bias[gc];
          if (EPI == 2) v = gelu_tanh(v);
          if (EPI == 3) v += res[(long)gr*ldc + gc];
          long o = coff + (long)gr*ldc + gc;
          if (OUT_BF16) Cb16[o] = f2b(v); else Cf[o] = v;
        }
      }
    }
  }

  // ---- fused FAVOR diag (K/Q segments) + REDU init (TM=128 only)
  if constexpr (DIAGM>0){
    if (bz == 0 && blockIdx.x == 0 && blockIdx.y == 0 && tid == 0) maxu[0] = 0u;
    if (bz < 2){
      const long soff = (long)bz * (long)R * diagH;
      #pragma unroll
      for (int m=0;m<4;m++)
        #pragma unroll
        for (int e=0;e<4;e++){
          int r = WRO + m*16 + lg*4 + e;
          float s = 0.f;
          #pragma unroll
          for (int nn=0;nn<CF;nn++) s = fmaf(acc[m][nn][e], acc[m][nn][e], s);
          #pragma unroll
          for (int o=1;o<16;o<<=1) s += __shfl_xor(s, o);
          if (lr==0){
            if constexpr (DIAGM==2){
              int gr = r0 + r;
              int bb = gr / nseq, ni = gr - bb*nseq;
              int hh = (int)blockIdx.x*2 + wc;
              diagp[soff + ((long)bb*diagH + hh)*nseq + ni] = dnn*s;
            } else {
              dg2[r][wc] = s;
            }
          }
        }
      if constexpr (DIAGM==1){
        __syncthreads();
        if (tid < 128){
          int gr = r0 + tid;
          int bb = gr / nseq, ni = gr - bb*nseq;
          int hh = (int)blockIdx.x;
          diagp[soff + ((long)bb*diagH + hh)*nseq + ni] = dnn*(dg2[tid][0] + dg2[tid][1]);
        }
      }
    }
  }
}

// ---------------- fused Q-side v8: Q in regs, split P/C LDS buffers, 2 barriers/chunk ----
// 8 waves/block (wr row-half x wc col-quadrant), 64 rows, grid (bh, ny) XCD pairing.
template<int DH, int MP, int MM, int NCH, int NOUT>
__global__ __launch_bounds__(512) void k_qout(
    const unsigned short* __restrict__ Qb,   // [rows][I], head offset h*DH
    const unsigned short* __restrict__ proj, // [MP][DH] bf16 (pad rows zero)
    const unsigned short* __restrict__ CTXT, // per bh: [DH][MP]
    const float* __restrict__ diagq,         // [bh*n]
    const float* __restrict__ ksum,          // [bh*MP]
    unsigned short* __restrict__ out,        // [rows][I]
    float dn, float ratio, float eps,
    int H, int n, int I)
{
  constexpr int QP = DH + 8;
  constexpr int NST = DH/32;                       // k-frags for dd
  constexpr int NQS = (64*(DH/8) + 511)/512;       // proj staging iters
  constexpr int NCS = (DH*8 + 511)/512;            // CTXT staging iters
  __shared__ unsigned short Pb[64][QP];            // proj chunk
  __shared__ unsigned short Cb[DH][72];            // CTXT chunk
  __shared__ unsigned short qp[64][72];
  __shared__ float ks_all[MP];
  __shared__ float diag_lds[64], rmax4[4][64], qs4[4][64], dinv_lds[64];
  const int tid = threadIdx.x;
  const int bz = blockIdx.x;               // head on x: same-bz blocks share an XCD
  const int b = bz / H, h = bz - b*H;
  const int ni0 = blockIdx.y*64;
  const int wid = tid>>6, lane = tid&63;
  const int wr = wid>>2, wc = wid&3;
  const int lr = lane&15, lg = lane>>4;
  const long ctxoff = (long)bz*DH*MP;

  u16x8 rP[NQS], rC[NCS];
  auto ldP = [&](int mc){
    #pragma unroll
    for (int it=0; it<NQS; ++it){
      int idx = tid + it*512;
      int c = idx/(DH/8), seg = idx%(DH/8);
      int mg = mc*64 + c;
      rP[it] = (mg < MP) ? *reinterpret_cast<const u16x8*>(proj + (long)mg*DH + seg*8) : u16x8{};
    }
  };
  auto stP = [&](){
    #pragma unroll
    for (int it=0; it<NQS; ++it){
      int idx = tid + it*512;
      int c = idx/(DH/8), seg = idx%(DH/8);
      *reinterpret_cast<u16x8*>(&Pb[c][seg*8]) = rP[it];
    }
  };
  auto ldC = [&](int mc){
    #pragma unroll
    for (int it=0; it<NCS; ++it){
      int idx = tid + it*512;
      int c = idx>>3, kseg = idx&7;
      int kg = mc*64 + kseg*8;
      rC[it] = (kg < MP) ? *reinterpret_cast<const u16x8*>(CTXT + ctxoff + (long)c*MP + kg) : u16x8{};
    }
  };
  auto stC = [&](){
    #pragma unroll
    for (int it=0; it<NCS; ++it){
      int idx = tid + it*512;
      int c = idx>>3, kseg = idx&7;
      *reinterpret_cast<u16x8*>(&Cb[c][kseg*8]) = rC[it];
    }
  };

  // Q fragments -> registers (rows wr*32+m*16+lr fixed per thread)
  const unsigned short* Qp = Qb + ((long)(b*n + ni0))*I + h*DH;
  bf16x8 aq[2][NST];
  #pragma unroll
  for (int m=0;m<2;m++){
    int qrow = wr*32 + m*16 + lr;
    #pragma unroll
    for (int ks=0;ks<NST;ks++)
      aq[m][ks] = *reinterpret_cast<const bf16x8*>(Qp + (long)qrow*I + ks*32 + lg*8);
  }
  for (int i=tid;i<MP;i+=512) ks_all[i] = ksum[(long)bz*MP + i];
  if (tid < 64) diag_lds[tid] = diagq[(long)bz*n + ni0 + tid];
  ldP(0);
  stP();
  __syncthreads();   // diag, ks_all, Pb(proj 0) ready

  // ---- pass 1: row max over all chunks (pipelined proj staging)
  float rmax[2][4];
  #pragma unroll
  for (int m=0;m<2;m++)
    #pragma unroll
    for (int e=0;e<4;e++) rmax[m][e] = -INFINITY;
  for (int mc=0; mc<NCH; ++mc){
    if (mc+1 < NCH) ldP(mc+1);
    f32x4 dacc[2] = {};
    __builtin_amdgcn_s_setprio(1);
    #pragma unroll
    for (int ks=0; ks<NST; ++ks){
      bf16x8 bf_ = *reinterpret_cast<const bf16x8*>(&Pb[wc*16+lr][ks*32 + lg*8]);
      #pragma unroll
      for (int m=0;m<2;m++)
        dacc[m] = __builtin_amdgcn_mfma_f32_16x16x32_bf16(aq[m][ks], bf_, dacc[m], 0, 0, 0);
    }
    __builtin_amdgcn_s_setprio(0);
    {
      int col = mc*64 + wc*16 + lr;
      if (col < MM){
        #pragma unroll
        for (int m=0;m<2;m++)
          #pragma unroll
          for (int e=0;e<4;e++) rmax[m][e] = fmaxf(rmax[m][e], dacc[m][e]*dn);
      }
    }
    __syncthreads();
    if (mc+1 < NCH){ stP(); __syncthreads(); }
  }
  #pragma unroll
  for (int m=0;m<2;m++)
    #pragma unroll
    for (int e=0;e<4;e++){
      #pragma unroll
      for (int o=1;o<16;o<<=1) rmax[m][e] = fmaxf(rmax[m][e], __shfl_xor(rmax[m][e], o));
      if (lr==0) rmax4[wc][wr*32+m*16+lg*4+e] = rmax[m][e];
    }
  __syncthreads();
  if (tid < 64)
    rmax4[0][tid] = fmaxf(fmaxf(rmax4[0][tid], rmax4[1][tid]),
                          fmaxf(rmax4[2][tid], rmax4[3][tid]));
  ldP(0);
  __syncthreads();
  stP();
  __syncthreads();   // Pb(proj 0) + rmax ready

  // ---- pass 2: dd -> exp -> qp; PV; 2 barriers per chunk (split P/C buffers)
  float qsum[2][4] = {};
  f32x4 oacc[2][NOUT] = {};
  for (int mc=0; mc<NCH; ++mc){
    ldC(mc);
    f32x4 dacc[2] = {};
    __builtin_amdgcn_s_setprio(1);
    #pragma unroll
    for (int ks=0; ks<NST; ++ks){
      bf16x8 bf_ = *reinterpret_cast<const bf16x8*>(&Pb[wc*16+lr][ks*32 + lg*8]);
      #pragma unroll
      for (int m=0;m<2;m++)
        dacc[m] = __builtin_amdgcn_mfma_f32_16x16x32_bf16(aq[m][ks], bf_, dacc[m], 0, 0, 0);
    }
    __builtin_amdgcn_s_setprio(0);
    // exp -> qp LDS (+ dinv partials)
    {
      int lc = wc*16 + lr;
      int col = mc*64 + lc;
      bool valid = (col < MM);
      float kv = valid ? ks_all[col] : 0.f;
      #pragma unroll
      for (int m=0;m<2;m++)
        #pragma unroll
        for (int e=0;e<4;e++){
          int row = wr*32+m*16+lg*4+e;
          float v = 0.f;
          if (valid){
            v = ratio*(expf(dacc[m][e]*dn - diag_lds[row] - rmax4[0][row]) + eps);
            qsum[m][e] = fmaf(v, kv, qsum[m][e]);
          }
          qp[row][lc] = f2b(v);
        }
    }
    stC();                       // write CTXT chunk into Cb (disjoint from Pb)
    if (mc+1 < NCH) ldP(mc+1);   // issue next proj loads
    __syncthreads();             // A: qp + Cb ready; Pb reads done
    __builtin_amdgcn_s_setprio(1);
    #pragma unroll
    for (int ks=0; ks<2; ++ks){
      bf16x8 af[2];
      #pragma unroll
      for (int m=0;m<2;m++) af[m] = *reinterpret_cast<const bf16x8*>(&qp[wr*32+m*16+lr][ks*32+lg*8]);
      #pragma unroll
      for (int nn=0;nn<NOUT;nn++){
        bf16x8 bf_ = *reinterpret_cast<const bf16x8*>(&Cb[wc*(DH/4)+nn*16+lr][ks*32 + lg*8]);
        #pragma unroll
        for (int m=0;m<2;m++)
          oacc[m][nn] = __builtin_amdgcn_mfma_f32_16x16x32_bf16(af[m], bf_, oacc[m][nn], 0, 0, 0);
      }
    }
    __builtin_amdgcn_s_setprio(0);
    if (mc+1 < NCH) stP();       // write next proj into Pb (PV doesn't touch Pb)
    __syncthreads();             // B: Pb ready for next dd; Cb/qp reads done
  }

  #pragma unroll
  for (int m=0;m<2;m++)
    #pragma unroll
    for (int e=0;e<4;e++){
      float s = qsum[m][e];
      #pragma unroll
      for (int o=1;o<16;o<<=1) s += __shfl_xor(s, o);
      if (lr==0) qs4[wc][wr*32+m*16+lg*4+e] = s;
    }
  __syncthreads();
  if (tid < 64) dinv_lds[tid] = 1.0f/(qs4[0][tid] + qs4[1][tid] + qs4[2][tid] + qs4[3][tid]);
  __syncthreads();

  unsigned short* Op = out + ((long)(b*n + ni0))*I + h*DH;
  #pragma unroll
  for (int m=0;m<2;m++)
    #pragma unroll
    for (int e=0;e<4;e++){
      int row = wr*32+m*16+lg*4+e;
      float di = dinv_lds[row];
      #pragma unroll
      for (int nn=0;nn<NOUT;nn++){
        int c = wc*(DH/4)+nn*16+lr;
        Op[(long)row*I + c] = f2b(oacc[m][nn][e]*di);
      }
    }
}

// ---------------- final mean over s ----------------
__global__ __launch_bounds__(256) void k_mean(const float* __restrict__ X,
    float* __restrict__ out)
{
  int idx = blockIdx.x*256 + threadIdx.x;   // b*128+f
  int f = idx & 127, b = idx >> 7;
  const float* p = X + (long)b*256*128 + f;
  float s = 0.f;
  for (int i=0;i<256;i++) s += p[i*128];
  out[idx] = s*(1.0f/256.0f);
}

// ---------------- host-side stage driver ----------------
struct StageP {
  const float *ln1w,*ln1b,*wob,*ln2w,*ln2b,*f1b,*f2b;
  const unsigned short *wkqvT,*woT,*f1T,*f2T,*projb;
  int n, D, H, dh, I, M, Mp;
};

template<int DH, int MP, int MM, int NCH, int NOUT, int DGM>
static void run_stage(const StageP& P, float* X, unsigned short* LNb,
    unsigned short* KQVb, unsigned short* DDk, unsigned short* CTXT,
    unsigned short* ATTNb, unsigned short* FFHb,
    float* KPSUM, float* DIAG, unsigned* REDU,
    hipStream_t stream)
{
  const int B = 64;
  const int rows = B*P.n;
  const int bh = B*P.H;
  const int bhn = bh*P.n;
  const float dn = powf((float)P.dh, -0.25f);
  const float dnn = 0.5f*dn*dn;
  const float ratio = 1.0f/sqrtf((float)P.M);
  const float eps = 1e-4f;

  const unsigned short* Kb = KQVb;
  const unsigned short* Qb = KQVb + (long)rows*P.I;
  const unsigned short* Vb = KQVb + 2L*rows*P.I;
  const float* DIAGK = DIAG;
  const float* DIAGQ = DIAG + bhn;

  for (int l=0;l<4;l++){
    const float* ln1w = P.ln1w + (long)l*P.D;
    const float* ln1b = P.ln1b + (long)l*P.D;
    const float* wob  = P.wob  + (long)l*P.D;
    const float* ln2w = P.ln2w + (long)l*P.D;
    const float* ln2b = P.ln2b + (long)l*P.D;
    const float* f1b  = P.f1b  + (long)l*4*P.D;
    const float* f2b_ = P.f2b  + (long)l*P.D;
    const unsigned short* wkqvT = P.wkqvT + (long)l*3*P.D*P.I;
    const unsigned short* woT = P.woT + (long)l*P.I*P.D;
    const unsigned short* f1T = P.f1T + (long)l*P.D*4*P.D;
    const unsigned short* f2T = P.f2T + (long)l*4*P.D*P.D;
    const unsigned short* pjb = P.projb + (long)l*P.Mp*P.dh;

    // LN1 (once) -> LNb
    k_ln<<<dim3((rows+3)/4),dim3(256),0,stream>>>(X, ln1w, ln1b, LNb, rows, P.D);
    // K,Q,V projection + diag epilogue + REDU init
    dim3 gq(P.I/128, rows/128, 3);
    k_mgemm<false,true,0,true,false,0,false,DGM,128><<<gq,dim3(256),0,stream>>>(
        LNb, wkqvT, KQVb, nullptr,nullptr, nullptr,nullptr, REDU, nullptr,
        DIAG, dnn, P.n, P.H,
        0,0,0, 1.f, 1, rows, P.I, P.D,
        0,0,(long)P.D,
        (long)P.I*P.D,0,(long)P.D,
        (long)rows*P.I,0,(long)P.I);
    // dd_k -> DDk (bf16), fused global max
    dim3 gdd((P.Mp+127)/128, P.n/128, bh);
    k_mgemm<false,true,0,true,false,1,false,0,128><<<gdd,dim3(256),0,stream>>>(
        Kb, pjb, DDk, nullptr,nullptr, nullptr,nullptr, REDU, nullptr,
        nullptr, 0.f, 0, 0,
        0,0,0, dn, P.H, P.n, P.Mp, P.dh,
        (long)P.n*P.I, (long)P.dh, (long)P.I,
        0, 0, (long)P.dh,
        (long)P.H*P.n*P.Mp, (long)P.n*P.Mp, (long)P.Mp);
    // CTXT = V^T @ kp with exp fused on B-stage + fused kpsum
    dim3 gctx((P.Mp+127)/128, (P.dh+127)/128, bh);
    k_mgemm<true,false,0,true,true,0,true,0,128><<<gctx,dim3(256),0,stream>>>(
        Vb, DDk, CTXT, nullptr,nullptr, DIAGK, REDU, nullptr, KPSUM,
        nullptr, 0.f, 0, 0,
        ratio, eps, P.M,
        1.f, P.H, P.dh, P.Mp, P.n,
        (long)P.n*P.I, (long)P.dh, (long)P.I,
        (long)P.H*P.n*P.Mp, (long)P.n*P.Mp, (long)P.Mp,
        (long)P.H*P.dh*P.Mp, (long)P.dh*P.Mp, (long)P.Mp);
    // fused Q side: 8 waves/block; grid (bh, ny) so same-head blocks share an XCD's L2
    dim3 gqo(bh, P.n/64, 1);
    k_qout<DH,MP,MM,NCH,NOUT><<<gqo,dim3(512),0,stream>>>(
        Qb, pjb, CTXT, DIAGQ, KPSUM, ATTNb, dn, ratio, eps, P.H, P.n, P.I);
    // x = x + attn @ wo + wob  (TM=64)
    dim3 gwo(P.D/128, rows/64, 1);
    k_mgemm<false,true,3,false,false,0,false,0,64><<<gwo,dim3(256),0,stream>>>(
        ATTNb, woT, X, wob, X, nullptr,nullptr, nullptr,nullptr,
        nullptr, 0.f, 0, 0,
        0,0,0, 1.f, 1, rows, P.D, P.I, 0,0,(long)P.I, 0,0,(long)P.I, 0,0,(long)P.D);
    // LN2 (once) -> LNb
    k_ln<<<dim3((rows+3)/4),dim3(256),0,stream>>>(X, ln2w, ln2b, LNb, rows, P.D);
    // FF1 (gelu)
    dim3 gf1(4*P.D/128, rows/128, 1);
    k_mgemm<false,true,2,true,false,0,false,0,128><<<gf1,dim3(256),0,stream>>>(
        LNb, f1T, FFHb, f1b, nullptr, nullptr,nullptr, nullptr,nullptr,
        nullptr, 0.f, 0, 0,
        0,0,0, 1.f, 1, rows, 4*P.D, P.D, 0,0,(long)P.D, 0,0,(long)P.D, 0,0,(long)(4*P.D));
    // FF2 + residual (TM=64)
    dim3 gf2(P.D/128, rows/64, 1);
    k_mgemm<false,true,3,false,false,0,false,0,64><<<gf2,dim3(256),0,stream>>>(
        FFHb, f2T, X, f2b_, X, nullptr,nullptr, nullptr,nullptr,
        nullptr, 0.f, 0, 0,
        0,0,0, 1.f, 1, rows, P.D, 4*P.D, 0,0,(long)(4*P.D), 0,0,(long)(4*P.D), 0,0,(long)P.D);
  }
}

// ---------------- entry ----------------
extern "C" void kernel_launch(void* const* d_in, const int* in_sizes, int n_in,
                              void* d_out, int out_size, void* d_ws, size_t ws_size,
                              hipStream_t stream)
{
  const float* x     = (const float*)d_in[0];
  const float* lin_w = (const float*)d_in[1];
  const float* lin_b = (const float*)d_in[2];

  char* wsb = (char*)d_ws;
  size_t off = 0;
  auto alloc = [&](size_t bytes)->void*{ void* p = wsb + off; off += (bytes + 255) & ~(size_t)255; return p; };
  float* X     = (float*)alloc(8388608);
  float* X2    = (float*)alloc(8388608);
  unsigned short* LNb   = (unsigned short*)alloc(4194304);
  unsigned short* KQVb  = (unsigned short*)alloc(31457280);   // [K][Q][V] bf16
  unsigned short* DDk   = (unsigned short*)alloc(52428800);   // bf16 dd_k (aliased as FF hidden)
  unsigned short* CTXT  = (unsigned short*)alloc(52428800);
  unsigned short* ATTNb = (unsigned short*)alloc(10485760);
  unsigned short* WKQV1 = (unsigned short*)alloc(3932160);    // [L][3][I][D]
  unsigned short* WO1T  = (unsigned short*)alloc(1310720);
  unsigned short* F11T  = (unsigned short*)alloc(2097152);
  unsigned short* F21T  = (unsigned short*)alloc(2097152);
  unsigned short* WKQV2 = (unsigned short*)alloc(786432);
  unsigned short* WO2T  = (unsigned short*)alloc(262144);
  unsigned short* F12T  = (unsigned short*)alloc(524288);
  unsigned short* F22T  = (unsigned short*)alloc(524288);
  unsigned short* PJ1   = (unsigned short*)alloc(655360);
  unsigned short* PJ2   = (unsigned short*)alloc(147456);
  float* KPSUM = (float*)alloc(819200);
  float* DIAG  = (float*)alloc(524288);
  unsigned* REDU = (unsigned*)alloc(256);
  unsigned short* FFHb = DDk;   // FF hidden aliases DDk (dead during FF)
  if (ws_size < off) return;

  // ---- merged weight conversions ----
  WTJobs jt;
  jt.src[0]=(const float*)d_in[6];  jt.dst[0]=WKQV1+0L*640*256;  jt.K[0]=256; jt.N[0]=640;  jt.lstr[0]=3L*640*256;
  jt.src[1]=(const float*)d_in[5];  jt.dst[1]=WKQV1+1L*640*256;  jt.K[1]=256; jt.N[1]=640;  jt.lstr[1]=3L*640*256;
  jt.src[2]=(const float*)d_in[7];  jt.dst[2]=WKQV1+2L*640*256;  jt.K[2]=256; jt.N[2]=640;  jt.lstr[2]=3L*640*256;
  jt.src[3]=(const float*)d_in[8];  jt.dst[3]=WO1T;              jt.K[3]=640; jt.N[3]=256;  jt.lstr[3]=640L*256;
  jt.src[4]=(const float*)d_in[12]; jt.dst[4]=F11T;              jt.K[4]=256; jt.N[4]=1024; jt.lstr[4]=1024L*256;
  jt.src[5]=(const float*)d_in[14]; jt.dst[5]=F21T;              jt.K[5]=1024;jt.N[5]=256;  jt.lstr[5]=1024L*256;
  jt.src[6]=(const float*)d_in[20]; jt.dst[6]=WKQV2+0L*256*128;  jt.K[6]=128; jt.N[6]=256;  jt.lstr[6]=3L*256*128;
  jt.src[7]=(const float*)d_in[19]; jt.dst[7]=WKQV2+1L*256*128;  jt.K[7]=128; jt.N[7]=256;  jt.lstr[7]=3L*256*128;
  jt.src[8]=(const float*)d_in[21]; jt.dst[8]=WKQV2+2L*256*128;  jt.K[8]=128; jt.N[8]=256;  jt.lstr[8]=3L*256*128;
  jt.src[9]=(const float*)d_in[22]; jt.dst[9]=WO2T;              jt.K[9]=256; jt.N[9]=128;  jt.lstr[9]=256L*128;
  jt.src[10]=(const float*)d_in[26];jt.dst[10]=F12T;             jt.K[10]=128;jt.N[10]=512; jt.lstr[10]=512L*128;
  jt.src[11]=(const float*)d_in[28];jt.dst[11]=F22T;             jt.K[11]=512;jt.N[11]=128; jt.lstr[11]=512L*128;
  k_wtall<<<dim3(256,12,4),dim3(256),0,stream>>>(jt);
  {
    long t1 = 4L*640*128;
    k_projconv<<<dim3((int)((t1+255)/256)),dim3(256),0,stream>>>((const float*)d_in[16], PJ1, 620, 640, 128, t1);
    long t2 = 4L*288*64;
    k_projconv<<<dim3((int)((t2+255)/256)),dim3(256),0,stream>>>((const float*)d_in[30], PJ2, 266, 288, 64, t2);
  }

  StageP T;
  T.ln1w=(const float*)d_in[3];  T.ln1b=(const float*)d_in[4];
  T.wob=(const float*)d_in[9];
  T.ln2w=(const float*)d_in[10]; T.ln2b=(const float*)d_in[11];
  T.f1b=(const float*)d_in[13];  T.f2b=(const float*)d_in[15];
  T.wkqvT=WKQV1; T.woT=WO1T; T.f1T=F11T; T.f2T=F21T; T.projb=PJ1;
  T.n=128; T.D=256; T.H=5; T.dh=128; T.I=640; T.M=620; T.Mp=640;

  StageP Ms;
  Ms.ln1w=(const float*)d_in[17]; Ms.ln1b=(const float*)d_in[18];
  Ms.wob=(const float*)d_in[23];
  Ms.ln2w=(const float*)d_in[24]; Ms.ln2b=(const float*)d_in[25];
  Ms.f1b=(const float*)d_in[27];  Ms.f2b=(const float*)d_in[29];
  Ms.wkqvT=WKQV2; Ms.woT=WO2T; Ms.f1T=F12T; Ms.f2T=F22T; Ms.projb=PJ2;
  Ms.n=256; Ms.D=128; Ms.H=4; Ms.dh=64; Ms.I=256; Ms.M=266; Ms.Mp=288;

  k_embed<<<dim3(8192),dim3(256),0,stream>>>(x, lin_w, lin_b, X);
  run_stage<128,640,620,10,2,1>(T, X, LNb, KQVb, DDk, CTXT, ATTNb, FFHb,
            KPSUM, DIAG, REDU, stream);
  k_transpose_pe<<<dim3(4,8,64),dim3(256),0,stream>>>(X, X2);
  run_stage<64,288,266,5,1,2>(Ms, X2, LNb, KQVb, DDk, CTXT, ATTNb, FFHb,
            KPSUM, DIAG, REDU, stream);
  k_mean<<<dim3(32),dim3(256),0,stream>>>(X2, (float*)d_out);
}